// Round 1
// baseline (592.128 us; speedup 1.0000x reference)
//
#include <hip/hip_runtime.h>
#include <hip/hip_bf16.h>

#define NN 256
#define CC 128
#define NHEADS 4
#define HDIM 32
#define TR 16

// ---------------- LayerNorm: one wave per row ----------------
__global__ __launch_bounds__(256) void ln_kernel(
        const float* __restrict__ x, const float* __restrict__ w_ln,
        const float* __restrict__ b_ln, float* __restrict__ h) {
    int row = blockIdx.x * 4 + (threadIdx.x >> 6);
    int lane = threadIdx.x & 63;
    float2 v = reinterpret_cast<const float2*>(x + (size_t)row * CC)[lane];
    float s = v.x + v.y;
    float sq = v.x * v.x + v.y * v.y;
#pragma unroll
    for (int off = 32; off >= 1; off >>= 1) {
        s += __shfl_xor(s, off);
        sq += __shfl_xor(sq, off);
    }
    float mean = s * (1.0f / CC);
    float var = sq * (1.0f / CC) - mean * mean;
    float rstd = rsqrtf(var + 1e-5f);
    int c0 = lane * 2;
    float2 o;
    o.x = (v.x - mean) * rstd * w_ln[c0] + b_ln[c0];
    o.y = (v.y - mean) * rstd * w_ln[c0 + 1] + b_ln[c0 + 1];
    reinterpret_cast<float2*>(h + (size_t)row * CC)[lane] = o;
}

// ---------------- Projections q/k/v/g: 16-row tile, h in LDS ----------------
// blockIdx.y selects the matrix. q/k/v written in [b*NH+head][pos][d] layout.
__global__ __launch_bounds__(256) void proj_kernel(
        const float* __restrict__ h,
        const float* __restrict__ w_q, const float* __restrict__ w_k,
        const float* __restrict__ w_v, const float* __restrict__ w_g,
        float* __restrict__ q, float* __restrict__ k,
        float* __restrict__ v, float* __restrict__ g) {
    __shared__ float hs[TR * CC];
    int mat = blockIdx.y;
    const float* __restrict__ w = (mat == 0) ? w_q : (mat == 1) ? w_k
                                : (mat == 2) ? w_v : w_g;
    int row0 = blockIdx.x * TR;
    for (int idx = threadIdx.x; idx < TR * CC / 4; idx += 256) {
        reinterpret_cast<float4*>(hs)[idx] =
            reinterpret_cast<const float4*>(h + (size_t)row0 * CC)[idx];
    }
    __syncthreads();
    int col = threadIdx.x & 127;
    int rh = threadIdx.x >> 7;   // 0..1, each covers 8 rows
    const float* __restrict__ wrow = w + (size_t)col * CC;
    float acc[8] = {0.f, 0.f, 0.f, 0.f, 0.f, 0.f, 0.f, 0.f};
    for (int kk = 0; kk < CC; kk += 4) {
        float4 wv = *reinterpret_cast<const float4*>(wrow + kk);
#pragma unroll
        for (int r = 0; r < 8; ++r) {
            float4 hv = *reinterpret_cast<const float4*>(&hs[(rh * 8 + r) * CC + kk]);
            acc[r] += hv.x * wv.x + hv.y * wv.y + hv.z * wv.z + hv.w * wv.w;
        }
    }
#pragma unroll
    for (int r = 0; r < 8; ++r) {
        int row = row0 + rh * 8 + r;
        if (mat == 3) {
            g[(size_t)row * CC + col] = 1.0f / (1.0f + __expf(-acc[r]));
        } else {
            int b = row >> 8, p = row & 255, head = col >> 5, d = col & 31;
            size_t off = (((size_t)(b * NHEADS + head)) * NN + p) * HDIM + d;
            if (mat == 0)      q[off] = acc[r];
            else if (mat == 1) k[off] = acc[r];
            else               v[off] = acc[r];
        }
    }
}

// ---------------- Pair bias, stored transposed: biasT[head][k][q] ----------------
__global__ __launch_bounds__(256) void bias_kernel(
        const float* __restrict__ h, const float* __restrict__ w_b,
        float* __restrict__ biasT) {
    int t = blockIdx.x * 256 + threadIdx.x;   // t = i*NN + j
    int i = t >> 8, j = t & 255;
    const float* hrow = h + (size_t)t * CC;
    float a0 = 0.f, a1 = 0.f, a2 = 0.f, a3 = 0.f;
    for (int kk = 0; kk < CC; kk += 4) {
        float4 hv = *reinterpret_cast<const float4*>(hrow + kk);
        float4 w0 = *reinterpret_cast<const float4*>(w_b + 0 * CC + kk);
        float4 w1 = *reinterpret_cast<const float4*>(w_b + 1 * CC + kk);
        float4 w2 = *reinterpret_cast<const float4*>(w_b + 2 * CC + kk);
        float4 w3 = *reinterpret_cast<const float4*>(w_b + 3 * CC + kk);
        a0 += hv.x * w0.x + hv.y * w0.y + hv.z * w0.z + hv.w * w0.w;
        a1 += hv.x * w1.x + hv.y * w1.y + hv.z * w1.z + hv.w * w1.w;
        a2 += hv.x * w2.x + hv.y * w2.y + hv.z * w2.z + hv.w * w2.w;
        a3 += hv.x * w3.x + hv.y * w3.y + hv.z * w3.z + hv.w * w3.w;
    }
    // bias[h][i=q][j=k]  ->  biasT[h][j][i] so attention reads coalesced over q
    biasT[0 * NN * NN + j * NN + i] = a0;
    biasT[1 * NN * NN + j * NN + i] = a1;
    biasT[2 * NN * NN + j * NN + i] = a2;
    biasT[3 * NN * NN + j * NN + i] = a3;
}

// ---------------- Attention: block per (b,head), thread per q-row ----------------
__global__ __launch_bounds__(256) void attn_kernel(
        const float* __restrict__ qm, const float* __restrict__ km,
        const float* __restrict__ vm, const float* __restrict__ gm,
        const float* __restrict__ biasT, float* __restrict__ og) {
    __shared__ float Ks[NN * HDIM];
    __shared__ float Vs[NN * HDIM];
    int bh = blockIdx.x;            // b*NHEADS + head
    int b = bh >> 2, head = bh & 3;
    const float* kbase = km + (size_t)bh * (NN * HDIM);
    const float* vbase = vm + (size_t)bh * (NN * HDIM);
    for (int idx = threadIdx.x; idx < NN * HDIM / 4; idx += 256) {
        reinterpret_cast<float4*>(Ks)[idx] = reinterpret_cast<const float4*>(kbase)[idx];
        reinterpret_cast<float4*>(Vs)[idx] = reinterpret_cast<const float4*>(vbase)[idx];
    }
    __syncthreads();
    int qpos = threadIdx.x;
    const float* qrow = qm + (size_t)bh * (NN * HDIM) + qpos * HDIM;
    const float scale = 0.17677669529663687f;   // 1/sqrt(32)
    float qreg[HDIM];
#pragma unroll
    for (int d4 = 0; d4 < HDIM; d4 += 4) {
        float4 qv = *reinterpret_cast<const float4*>(qrow + d4);
        qreg[d4 + 0] = qv.x * scale;
        qreg[d4 + 1] = qv.y * scale;
        qreg[d4 + 2] = qv.z * scale;
        qreg[d4 + 3] = qv.w * scale;
    }
    const float* brow = biasT + (size_t)head * NN * NN + qpos;
    float m = -1e30f, l = 0.f;
    float acc[HDIM];
#pragma unroll
    for (int d = 0; d < HDIM; ++d) acc[d] = 0.f;
    for (int kp = 0; kp < NN; ++kp) {
        float s = brow[(size_t)kp * NN];
        const float4* krow = reinterpret_cast<const float4*>(Ks + kp * HDIM);
#pragma unroll
        for (int d4 = 0; d4 < 8; ++d4) {
            float4 kv = krow[d4];
            s += qreg[d4 * 4 + 0] * kv.x + qreg[d4 * 4 + 1] * kv.y
               + qreg[d4 * 4 + 2] * kv.z + qreg[d4 * 4 + 3] * kv.w;
        }
        float mn = fmaxf(m, s);
        float corr = __expf(m - mn);
        float p = __expf(s - mn);
        l = l * corr + p;
        const float4* vrow = reinterpret_cast<const float4*>(Vs + kp * HDIM);
#pragma unroll
        for (int d4 = 0; d4 < 8; ++d4) {
            float4 vv = vrow[d4];
            acc[d4 * 4 + 0] = acc[d4 * 4 + 0] * corr + p * vv.x;
            acc[d4 * 4 + 1] = acc[d4 * 4 + 1] * corr + p * vv.y;
            acc[d4 * 4 + 2] = acc[d4 * 4 + 2] * corr + p * vv.z;
            acc[d4 * 4 + 3] = acc[d4 * 4 + 3] * corr + p * vv.w;
        }
        m = mn;
    }
    float rl = 1.0f / l;
    size_t row = (size_t)b * NN + qpos;
    const float* grow = gm + row * CC + head * HDIM;
    float* orow = og + row * CC + head * HDIM;
#pragma unroll
    for (int d4 = 0; d4 < HDIM; d4 += 4) {
        float4 gv = *reinterpret_cast<const float4*>(grow + d4);
        float4 ov;
        ov.x = acc[d4 + 0] * rl * gv.x;
        ov.y = acc[d4 + 1] * rl * gv.y;
        ov.z = acc[d4 + 2] * rl * gv.z;
        ov.w = acc[d4 + 3] * rl * gv.w;
        *reinterpret_cast<float4*>(orow + d4) = ov;
    }
}

// ---------------- Output GEMM: out = og @ w_o^T ----------------
__global__ __launch_bounds__(256) void out_kernel(
        const float* __restrict__ og, const float* __restrict__ w_o,
        float* __restrict__ out) {
    __shared__ float os[TR * CC];
    int row0 = blockIdx.x * TR;
    for (int idx = threadIdx.x; idx < TR * CC / 4; idx += 256) {
        reinterpret_cast<float4*>(os)[idx] =
            reinterpret_cast<const float4*>(og + (size_t)row0 * CC)[idx];
    }
    __syncthreads();
    int col = threadIdx.x & 127;
    int rh = threadIdx.x >> 7;
    const float* wrow = w_o + (size_t)col * CC;
    float acc[8] = {0.f, 0.f, 0.f, 0.f, 0.f, 0.f, 0.f, 0.f};
    for (int kk = 0; kk < CC; kk += 4) {
        float4 wv = *reinterpret_cast<const float4*>(wrow + kk);
#pragma unroll
        for (int r = 0; r < 8; ++r) {
            float4 hv = *reinterpret_cast<const float4*>(&os[(rh * 8 + r) * CC + kk]);
            acc[r] += hv.x * wv.x + hv.y * wv.y + hv.z * wv.z + hv.w * wv.w;
        }
    }
#pragma unroll
    for (int r = 0; r < 8; ++r) {
        int row = row0 + rh * 8 + r;
        out[(size_t)row * CC + col] = acc[r];
    }
}

extern "C" void kernel_launch(void* const* d_in, const int* in_sizes, int n_in,
                              void* d_out, int out_size, void* d_ws, size_t ws_size,
                              hipStream_t stream) {
    const float* x    = (const float*)d_in[0];
    const float* w_ln = (const float*)d_in[1];
    const float* b_ln = (const float*)d_in[2];
    const float* w_b  = (const float*)d_in[3];
    const float* w_q  = (const float*)d_in[4];
    const float* w_k  = (const float*)d_in[5];
    const float* w_v  = (const float*)d_in[6];
    const float* w_g  = (const float*)d_in[7];
    const float* w_o  = (const float*)d_in[8];
    float* out = (float*)d_out;

    char* ws = (char*)d_ws;
    const size_t MB32 = (size_t)NN * NN * CC * sizeof(float);   // 32 MB
    float* h     = (float*)(ws + 0 * MB32);   // also og (h dead after bias/proj)
    float* q     = (float*)(ws + 1 * MB32);
    float* k     = (float*)(ws + 2 * MB32);
    float* v     = (float*)(ws + 3 * MB32);
    float* g     = (float*)(ws + 4 * MB32);
    float* biasT = (float*)(ws + 5 * MB32);   // 1 MB
    float* og    = h;

    ln_kernel<<<NN * NN / 4, 256, 0, stream>>>(x, w_ln, b_ln, h);
    proj_kernel<<<dim3(NN * NN / TR, 4), 256, 0, stream>>>(h, w_q, w_k, w_v, w_g,
                                                           q, k, v, g);
    bias_kernel<<<NN * NN / 256, 256, 0, stream>>>(h, w_b, biasT);
    attn_kernel<<<NN * NHEADS, 256, 0, stream>>>(q, k, v, g, biasT, og);
    out_kernel<<<NN * NN / TR, 256, 0, stream>>>(og, w_o, out);
}

// Round 2
// 188.098 us; speedup vs baseline: 3.1480x; 3.1480x over previous
//
#include <hip/hip_runtime.h>

#define NN 256
#define CC 128
#define NHEADS 4
#define HDIM 32

typedef short bf16x8 __attribute__((ext_vector_type(8)));
typedef float f32x4 __attribute__((ext_vector_type(4)));

__device__ __forceinline__ ushort f2b(float f) {
    uint u = __builtin_bit_cast(uint, f);
    uint r = (u + 0x7fffu + ((u >> 16) & 1u)) >> 16;
    return (ushort)r;
}
__device__ __forceinline__ float b2f(ushort s) {
    uint u = ((uint)s) << 16;
    return __builtin_bit_cast(float, u);
}

// ---------------- weight prep: f32 -> bf16, concat [q|k|v|g|bias|pad] ----------------
__global__ __launch_bounds__(128) void prep_kernel(
        const float* __restrict__ w_b, const float* __restrict__ w_q,
        const float* __restrict__ w_k, const float* __restrict__ w_v,
        const float* __restrict__ w_g, const float* __restrict__ w_o,
        ushort* __restrict__ wall, ushort* __restrict__ wo) {
    int row = blockIdx.x, col = threadIdx.x;
    if (row < 528) {
        float val;
        if (row < 128)      val = w_q[row * 128 + col];
        else if (row < 256) val = w_k[(row - 128) * 128 + col];
        else if (row < 384) val = w_v[(row - 256) * 128 + col];
        else if (row < 512) val = w_g[(row - 384) * 128 + col];
        else if (row < 516) val = w_b[(row - 512) * 128 + col];
        else                val = 0.0f;
        wall[row * 128 + col] = f2b(val);
    } else {
        int r = row - 528;
        wo[r * 128 + col] = f2b(w_o[r * 128 + col]);
    }
}

// ---------------- LayerNorm: one wave per row, bf16 out ----------------
__global__ __launch_bounds__(256) void ln_kernel(
        const float* __restrict__ x, const float* __restrict__ w_ln,
        const float* __restrict__ b_ln, ushort* __restrict__ h) {
    int row = blockIdx.x * 4 + (threadIdx.x >> 6);
    int lane = threadIdx.x & 63;
    float2 v = reinterpret_cast<const float2*>(x + (size_t)row * CC)[lane];
    float s = v.x + v.y;
    float sq = v.x * v.x + v.y * v.y;
#pragma unroll
    for (int off = 32; off >= 1; off >>= 1) {
        s += __shfl_xor(s, off);
        sq += __shfl_xor(sq, off);
    }
    float mean = s * (1.0f / CC);
    float var = sq * (1.0f / CC) - mean * mean;
    float rstd = rsqrtf(var + 1e-5f);
    int c0 = lane * 2;
    ushort2 o;
    o.x = f2b((v.x - mean) * rstd * w_ln[c0] + b_ln[c0]);
    o.y = f2b((v.y - mean) * rstd * w_ln[c0 + 1] + b_ln[c0 + 1]);
    reinterpret_cast<ushort2*>(h + (size_t)row * CC)[lane] = o;
}

// ---------------- fused projections via MFMA ----------------
// grid (1024, 3): block covers 64 m-rows; y covers n-tiles [y*11, y*11+11)
__global__ __launch_bounds__(256) void proj_kernel(
        const ushort* __restrict__ h, const ushort* __restrict__ wall,
        ushort* __restrict__ q, ushort* __restrict__ k, ushort* __restrict__ v,
        ushort* __restrict__ g, float* __restrict__ biasN) {
    __shared__ char hl[16384];   // 64 rows x 256B, XOR-swizzled
    int m0 = blockIdx.x * 64;
    int nt0 = blockIdx.y * 11;
    for (int idx = threadIdx.x; idx < 1024; idx += 256) {
        int byte = idx * 16, row = byte >> 8;
        *(float4*)(hl + (byte ^ ((row & 7) << 4))) =
            ((const float4*)(h + (size_t)m0 * 128))[idx];
    }
    __syncthreads();
    int w = threadIdx.x >> 6, lane = threadIdx.x & 63;
    int lo = lane & 15, hi = lane >> 4;
    int mrow = w * 16 + lo;
    bf16x8 a[4];
#pragma unroll
    for (int ks = 0; ks < 4; ++ks) {
        int byte = mrow * 256 + ks * 64 + hi * 16;
        a[ks] = *(const bf16x8*)(hl + (byte ^ ((mrow & 7) << 4)));
    }
    for (int nt = nt0; nt < nt0 + 11; ++nt) {
        f32x4 acc = {0.f, 0.f, 0.f, 0.f};
        const ushort* wb = wall + (size_t)(nt * 16 + lo) * 128;
#pragma unroll
        for (int ks = 0; ks < 4; ++ks) {
            bf16x8 bf = *(const bf16x8*)(wb + ks * 32 + hi * 8);
            acc = __builtin_amdgcn_mfma_f32_16x16x32_bf16(a[ks], bf, acc, 0, 0, 0);
        }
        int colbase = nt * 16;
#pragma unroll
        for (int r = 0; r < 4; ++r) {
            int m = m0 + w * 16 + hi * 4 + r;
            int col = colbase + lo;
            float val = acc[r];
            int bb2 = m >> 8, p = m & 255;
            if (colbase < 128) {
                int head = col >> 5, d = col & 31;
                q[(((size_t)(bb2 * 4 + head)) * 256 + p) * 32 + d] =
                    f2b(val * 0.17677669529663687f);
            } else if (colbase < 256) {
                int c = col - 128; int head = c >> 5, d = c & 31;
                k[(((size_t)(bb2 * 4 + head)) * 256 + p) * 32 + d] = f2b(val);
            } else if (colbase < 384) {
                int c = col - 256; int head = c >> 5, d = c & 31;
                v[(((size_t)(bb2 * 4 + head)) * 256 + p) * 32 + d] = f2b(val);
            } else if (colbase < 512) {
                g[(size_t)m * 128 + (col - 384)] = f2b(1.0f / (1.0f + __expf(-val)));
            } else {
                if (lo < 4) biasN[(size_t)lo * 65536 + m] = val;
            }
        }
    }
}

// ---------------- V transpose: v[bh][p][d] -> vt[bh][d][p] ----------------
__global__ __launch_bounds__(256) void vtrans_kernel(
        const ushort* __restrict__ v, ushort* __restrict__ vt) {
    __shared__ ushort tl[8192];
    int bh = blockIdx.x, tid = threadIdx.x;
    for (int idx = tid; idx < 1024; idx += 256)
        ((float4*)tl)[idx] = ((const float4*)(v + (size_t)bh * 8192))[idx];
    __syncthreads();
    int d = tid & 31, pb = tid >> 5;
#pragma unroll
    for (int j = 0; j < 4; ++j) {
        int p0 = pb * 32 + j * 8;
        ushort tmp[8];
#pragma unroll
        for (int i = 0; i < 8; ++i) tmp[i] = tl[(p0 + i) * 32 + d];
        *(float4*)(vt + (size_t)bh * 8192 + d * 256 + p0) = *(const float4*)tmp;
    }
}

// ---------------- attention: block = (bh, 64 q-rows), wave = 16 q-rows ----------------
__global__ __launch_bounds__(256) void attn_kernel(
        const ushort* __restrict__ qm, const ushort* __restrict__ km,
        const ushort* __restrict__ vtm, const ushort* __restrict__ gm,
        const float* __restrict__ biasN, ushort* __restrict__ og) {
    __shared__ char plds[4 * 8192];    // per-wave 8KB P tile, XOR-swizzled
    int blk = blockIdx.x, bh = blk >> 2, qb = blk & 3;
    int b = bh >> 2, head = bh & 3;
    int tid = threadIdx.x, w = tid >> 6, lane = tid & 63;
    int lo = lane & 15, hi = lane >> 4;
    int q0 = qb * 64 + w * 16;
    char* myp = plds + w * 8192;

    bf16x8 qa = *(const bf16x8*)(qm + ((size_t)bh * 256 + q0 + lo) * 32 + hi * 8);

    f32x4 s[16];
    const float* bb = biasN + (size_t)head * 65536 + (size_t)(q0 + hi * 4) * 256;
#pragma unroll
    for (int t = 0; t < 16; ++t) {
        f32x4 c;
#pragma unroll
        for (int r = 0; r < 4; ++r) c[r] = bb[r * 256 + t * 16 + lo];
        bf16x8 kf = *(const bf16x8*)(km + ((size_t)bh * 256 + t * 16 + lo) * 32 + hi * 8);
        s[t] = __builtin_amdgcn_mfma_f32_16x16x32_bf16(qa, kf, c, 0, 0, 0);
    }
    // online-free softmax (full row in registers across 16 lanes)
    float mx[4] = {-1e30f, -1e30f, -1e30f, -1e30f};
#pragma unroll
    for (int t = 0; t < 16; ++t)
#pragma unroll
        for (int r = 0; r < 4; ++r) mx[r] = fmaxf(mx[r], s[t][r]);
#pragma unroll
    for (int msk = 1; msk < 16; msk <<= 1)
#pragma unroll
        for (int r = 0; r < 4; ++r) mx[r] = fmaxf(mx[r], __shfl_xor(mx[r], msk));
    float l[4] = {0.f, 0.f, 0.f, 0.f};
#pragma unroll
    for (int t = 0; t < 16; ++t)
#pragma unroll
        for (int r = 0; r < 4; ++r) {
            float p = __expf(s[t][r] - mx[r]);
            s[t][r] = p;
            l[r] += p;
        }
#pragma unroll
    for (int msk = 1; msk < 16; msk <<= 1)
#pragma unroll
        for (int r = 0; r < 4; ++r) l[r] += __shfl_xor(l[r], msk);
    float rl[4];
#pragma unroll
    for (int r = 0; r < 4; ++r) rl[r] = 1.0f / l[r];
    // P -> LDS (bf16, swizzled); per-wave buffer, no barrier needed
#pragma unroll
    for (int t = 0; t < 16; ++t)
#pragma unroll
        for (int r = 0; r < 4; ++r) {
            int qr = hi * 4 + r;
            int byte = qr * 512 + (t * 16 + lo) * 2;
            *(ushort*)(myp + (byte ^ ((qr & 7) << 4))) = f2b(s[t][r]);
        }
    // PV
    f32x4 a0 = {0.f, 0.f, 0.f, 0.f}, a1 = {0.f, 0.f, 0.f, 0.f};
    const ushort* vtb = vtm + (size_t)bh * 8192;
#pragma unroll
    for (int kc = 0; kc < 8; ++kc) {
        int byte = lo * 512 + kc * 64 + hi * 16;
        bf16x8 pa = *(const bf16x8*)(myp + (byte ^ ((lo & 7) << 4)));
        bf16x8 v0 = *(const bf16x8*)(vtb + lo * 256 + kc * 32 + hi * 8);
        bf16x8 v1 = *(const bf16x8*)(vtb + (16 + lo) * 256 + kc * 32 + hi * 8);
        a0 = __builtin_amdgcn_mfma_f32_16x16x32_bf16(pa, v0, a0, 0, 0, 0);
        a1 = __builtin_amdgcn_mfma_f32_16x16x32_bf16(pa, v1, a1, 0, 0, 0);
    }
    // epilogue: normalize, gate, store og (bf16)
#pragma unroll
    for (int r = 0; r < 4; ++r) {
        int qg = q0 + hi * 4 + r;
        size_t mrow = (size_t)b * 256 + qg;
        int c0 = head * 32 + lo;
        float g0 = b2f(gm[mrow * 128 + c0]);
        float g1 = b2f(gm[mrow * 128 + 16 + c0]);
        og[mrow * 128 + c0]      = f2b(a0[r] * rl[r] * g0);
        og[mrow * 128 + 16 + c0] = f2b(a1[r] * rl[r] * g1);
    }
}

// ---------------- out GEMM: out = og @ w_o^T (bf16 MFMA, f32 out) ----------------
__global__ __launch_bounds__(256) void out_kernel(
        const ushort* __restrict__ og, const ushort* __restrict__ wo,
        float* __restrict__ out) {
    __shared__ char hl[16384];
    int m0 = blockIdx.x * 64;
    for (int idx = threadIdx.x; idx < 1024; idx += 256) {
        int byte = idx * 16, row = byte >> 8;
        *(float4*)(hl + (byte ^ ((row & 7) << 4))) =
            ((const float4*)(og + (size_t)m0 * 128))[idx];
    }
    __syncthreads();
    int w = threadIdx.x >> 6, lane = threadIdx.x & 63;
    int lo = lane & 15, hi = lane >> 4;
    int mrow = w * 16 + lo;
    bf16x8 a[4];
#pragma unroll
    for (int ks = 0; ks < 4; ++ks) {
        int byte = mrow * 256 + ks * 64 + hi * 16;
        a[ks] = *(const bf16x8*)(hl + (byte ^ ((mrow & 7) << 4)));
    }
#pragma unroll
    for (int nt = 0; nt < 8; ++nt) {
        f32x4 acc = {0.f, 0.f, 0.f, 0.f};
        const ushort* wb = wo + (size_t)(nt * 16 + lo) * 128;
#pragma unroll
        for (int ks = 0; ks < 4; ++ks) {
            bf16x8 bf = *(const bf16x8*)(wb + ks * 32 + hi * 8);
            acc = __builtin_amdgcn_mfma_f32_16x16x32_bf16(a[ks], bf, acc, 0, 0, 0);
        }
#pragma unroll
        for (int r = 0; r < 4; ++r) {
            int m = m0 + w * 16 + hi * 4 + r;
            out[(size_t)m * 128 + nt * 16 + lo] = acc[r];
        }
    }
}

extern "C" void kernel_launch(void* const* d_in, const int* in_sizes, int n_in,
                              void* d_out, int out_size, void* d_ws, size_t ws_size,
                              hipStream_t stream) {
    const float* x    = (const float*)d_in[0];
    const float* w_ln = (const float*)d_in[1];
    const float* b_ln = (const float*)d_in[2];
    const float* w_b  = (const float*)d_in[3];
    const float* w_q  = (const float*)d_in[4];
    const float* w_k  = (const float*)d_in[5];
    const float* w_v  = (const float*)d_in[6];
    const float* w_g  = (const float*)d_in[7];
    const float* w_o  = (const float*)d_in[8];
    float* out = (float*)d_out;

    char* ws = (char*)d_ws;
    const size_t MB16 = (size_t)65536 * 128 * sizeof(ushort);   // 16 MB
    ushort* h   = (ushort*)(ws + 0 * MB16);
    ushort* q   = (ushort*)(ws + 1 * MB16);
    ushort* k   = (ushort*)(ws + 2 * MB16);
    ushort* v   = (ushort*)(ws + 3 * MB16);
    ushort* g   = (ushort*)(ws + 4 * MB16);
    ushort* vt  = (ushort*)(ws + 5 * MB16);
    ushort* og  = (ushort*)(ws + 6 * MB16);
    float* biasN = (float*)(ws + 7 * MB16);                     // 1 MB
    ushort* wall = (ushort*)(ws + 7 * MB16 + (size_t)4 * 65536 * 4);
    ushort* wo   = wall + 528 * 128;

    prep_kernel<<<656, 128, 0, stream>>>(w_b, w_q, w_k, w_v, w_g, w_o, wall, wo);
    ln_kernel<<<65536 / 4, 256, 0, stream>>>(x, w_ln, b_ln, h);
    proj_kernel<<<dim3(1024, 3), 256, 0, stream>>>(h, wall, q, k, v, g, biasN);
    vtrans_kernel<<<1024, 256, 0, stream>>>(v, vt);
    attn_kernel<<<4096, 256, 0, stream>>>(q, k, vt, g, biasN, og);
    out_kernel<<<1024, 256, 0, stream>>>(og, wo, out);
}